// Round 5
// baseline (185.728 us; speedup 1.0000x reference)
//
#include <hip/hip_runtime.h>
#include <hip/hip_bf16.h>
#include <cmath>

#define Bsz 8
#define Csz 512
#define Lsz 4096
#define LPOOL 511
#define NEGV -1000000000.0f

typedef __attribute__((ext_vector_type(8))) short short8;
typedef __attribute__((ext_vector_type(4))) float float4v;

__device__ __forceinline__ float bf2f(short u) {
  unsigned int x = ((unsigned int)(unsigned short)u) << 16;
  return __builtin_bit_cast(float, x);
}

// fast tanh: 1 - 2/(e^{2x}+1); rel err ~1e-5, far below bf16 gemm noise
__device__ __forceinline__ float ftanh(float x) {
  float e = __expf(2.0f * x);
  return 1.0f - 2.0f * __builtin_amdgcn_rcpf(e + 1.0f);
}

// async global->LDS, 16B per lane; LDS dest = wave-uniform base + lane*16 (HW)
__device__ __forceinline__ void gl_lds16(const void* g, void* l) {
  __builtin_amdgcn_global_load_lds(
      (const __attribute__((address_space(1))) unsigned int*)g,
      (__attribute__((address_space(3))) unsigned int*)l, 16, 0, 0);
}

// ---------------------------------------------------------------------------
// prep: block 0 = mask-width detect; blocks 1..128 = W f32 -> Wts bf16 tiled.
__global__ __launch_bounds__(256) void prep(const unsigned char* __restrict__ mb,
    int* __restrict__ flag, const float* __restrict__ W,
    __hip_bfloat16* __restrict__ Wts) {
  const int tid = threadIdx.x;
  const int pb = blockIdx.x;
  if (pb == 0) {
    __shared__ int sf;
    if (tid == 0) sf = 0;
    __syncthreads();
    int f = 0;
    for (int i = tid; i < 4096; i += 256)
      if ((i & 3) && mb[i]) f = 1;
    if (f) atomicOr(&sf, 1);
    __syncthreads();
    if (tid == 0) *flag = sf;  // 0 = int32 mask, 1 = uint8 mask
  } else {
    int tg = (pb - 1) * 256 + tid;
    int d = tg >> 6, cg = tg & 63;
    float4 w0 = *(const float4*)(W + (size_t)d * 512 + cg * 8);
    float4 w1 = *(const float4*)(W + (size_t)d * 512 + cg * 8 + 4);
    __hip_bfloat16 hb[8];
    hb[0] = __float2bfloat16(w0.x); hb[1] = __float2bfloat16(w0.y);
    hb[2] = __float2bfloat16(w0.z); hb[3] = __float2bfloat16(w0.w);
    hb[4] = __float2bfloat16(w1.x); hb[5] = __float2bfloat16(w1.y);
    hb[6] = __float2bfloat16(w1.z); hb[7] = __float2bfloat16(w1.w);
    int nt = d >> 7, row = d & 127, ks = cg >> 2, seg = cg & 3;
    *(short8*)(Wts + (((size_t)nt * 16 + ks) * 512 + seg * 128 + row) * 8) = *(short8*)hb;
  }
}

// ---------------------------------------------------------------------------
// gemm_fused v5: 512 blocks x 256 thr (4 waves), 64 m-rows each, 104 KiB LDS
// (1 block/CU deterministic). Phase 1: x staged f32 into a 5-slot LDS ring
// via global_load_lds (pure DMA, depth-3 in flight = 24 KB/CU -> near-peak
// HBM stream, zero VALU on the load path), counted vmcnt + 1 barrier/chunk;
// consume = 8 strided ds_read_b32 + cvt + 1 ds_write_b128 into MFMA-tiled sA.
// No xbf write. Phase 2: identical to R4 (verified): 32m x 64n wave tiles,
// B double-buffered via global_load_lds w/ counted vmcnt(2), setprio MFMA,
// per-nt tanh epilogue in registers, no atomics.
__global__ __launch_bounds__(256, 1) void gemm_fused(
    const float* __restrict__ x, const __hip_bfloat16* __restrict__ Wts,
    const float* __restrict__ bias, const float* __restrict__ v,
    float* __restrict__ s) {
  __shared__ short8 sA[4096];                      // 64 KiB: A 64m x 512k tiled
  __shared__ __align__(16) float sXs[5][2048];     // 40 KiB ring: [32 c][64 l] f32

  const int tid = threadIdx.x;
  const int lane = tid & 63, wave = tid >> 6;
  const int mt = blockIdx.x;                       // 0..511
  const int b = mt >> 6;
  const int l0 = (mt & 63) << 6;                   // 64 l-rows per block

  const int quad = lane >> 4, sub = lane & 15;
  const int lr = lane & 15;                        // alias used in phase 2

  // ---------------- phase 1: DMA-ring transpose ----------------------------
  {
    // issue chunk k: 2 gl_lds per wave; instr j covers 4 c-rows of 64 floats.
    // src per lane: row c = k*32 + wave*8 + j*4 + quad, col = sub*4.
    // dest linear [c_local][64] f32 (lane*16B fills rows in order).
    const float* xb = x + (size_t)(b * Csz) * Lsz + l0;
#define ISSUE_CHUNK(k)                                                         \
  {                                                                            \
    const float* g0 = xb + (size_t)((k) * 32 + wave * 8 + quad) * Lsz + sub * 4; \
    gl_lds16(g0,           &sXs[(k) % 5][(wave * 8) * 64]);                    \
    gl_lds16(g0 + 4 * Lsz, &sXs[(k) % 5][(wave * 8 + 4) * 64]);                \
  }
    ISSUE_CHUNK(0)
    ISSUE_CHUNK(1)
    ISSUE_CHUNK(2)
    #pragma unroll
    for (int k = 0; k < 16; ++k) {
      if (k + 3 < 16) ISSUE_CHUNK(k + 3)
      // counted wait: chunk k's 2 loads landed (newer chunks stay in flight)
      if (k < 13)       asm volatile("s_waitcnt vmcnt(6)" ::: "memory");
      else if (k == 13) asm volatile("s_waitcnt vmcnt(4)" ::: "memory");
      else if (k == 14) asm volatile("s_waitcnt vmcnt(2)" ::: "memory");
      else              asm volatile("s_waitcnt vmcnt(0)" ::: "memory");
      __builtin_amdgcn_s_barrier();              // all waves' portions landed
      const float* bufp = &sXs[k % 5][0];
      // lane task: 8 consecutive c (octet = quad) for l = wave*16 + sub
      float tv[8];
      #pragma unroll
      for (int j = 0; j < 8; ++j) tv[j] = bufp[(quad * 8 + j) * 64 + wave * 16 + sub];
      __hip_bfloat16 ab[8];
      #pragma unroll
      for (int j = 0; j < 8; ++j) ab[j] = __float2bfloat16(tv[j]);
      sA[(k * 4 + quad) * 64 + wave * 16 + sub] = *(short8*)ab;
    }
#undef ISSUE_CHUNK
    __builtin_amdgcn_sched_barrier(0);
  }

  // preload bias/v fragments (compile-time nt/nf indexing; stays in VGPRs)
  const int mh = wave >> 1, nh = wave & 1;
  float bl[4][4], vl[4][4];
  #pragma unroll
  for (int nt = 0; nt < 4; ++nt)
    #pragma unroll
    for (int nf = 0; nf < 4; ++nf) {
      int n = nt * 128 + nh * 64 + nf * 16 + lr;
      bl[nt][nf] = bias[n];
      vl[nt][nf] = v[n];
    }

  __syncthreads();   // sA complete; ring dead -> reuse as sB
  short8 (*sB)[512] = (short8 (*)[512])sXs;        // 16 KiB of the dead ring
  // pre-stage B tile 0: 4 waves x 2 KB = full 8 KB tile
  {
    const __hip_bfloat16* gb = Wts + (size_t)(wave * 64 + lane) * 8;
    gl_lds16(gb,        &sB[0][wave * 64]);
    gl_lds16(gb + 2048, &sB[0][256 + wave * 64]);
  }
  __syncthreads();   // vmcnt(0)+lgkmcnt(0) drain -> exact vm counting below

  // ---------------- phase 2: nt-loop with A resident ------------------------
  float sp[2][4];
  #pragma unroll
  for (int mf = 0; mf < 2; ++mf)
    #pragma unroll
    for (int reg = 0; reg < 4; ++reg) sp[mf][reg] = 0.f;

  #pragma unroll
  for (int nt = 0; nt < 4; ++nt) {
    float4v acc[2][4];
    #pragma unroll
    for (int mf = 0; mf < 2; ++mf)
      #pragma unroll
      for (int nf = 0; nf < 4; ++nf) acc[mf][nf] = (float4v)0.f;

    #pragma unroll 2
    for (int ks = 0; ks < 16; ++ks) {
      const int idx = nt * 16 + ks;
      const int cur = idx & 1;
      if (idx < 63) {
        const __hip_bfloat16* gb =
            Wts + ((size_t)(idx + 1) << 12) + (size_t)(wave * 64 + lane) * 8;
        gl_lds16(gb,        &sB[cur ^ 1][wave * 64]);
        gl_lds16(gb + 2048, &sB[cur ^ 1][256 + wave * 64]);
        asm volatile("s_waitcnt vmcnt(2)" ::: "memory");  // cur tile landed
      } else {
        asm volatile("s_waitcnt vmcnt(0)" ::: "memory");
      }
      __builtin_amdgcn_sched_barrier(0);
      __builtin_amdgcn_s_barrier();        // all waves' portions visible
      short8 af[2], bfr[4];
      #pragma unroll
      for (int mf = 0; mf < 2; ++mf)
        af[mf] = sA[(ks * 4 + quad) * 64 + mh * 32 + mf * 16 + lr];
      #pragma unroll
      for (int nf = 0; nf < 4; ++nf)
        bfr[nf] = sB[cur][quad * 128 + nh * 64 + nf * 16 + lr];
      __builtin_amdgcn_s_setprio(1);
      #pragma unroll
      for (int mf = 0; mf < 2; ++mf)
        #pragma unroll
        for (int nf = 0; nf < 4; ++nf)
          acc[mf][nf] = __builtin_amdgcn_mfma_f32_16x16x32_bf16(
              af[mf], bfr[nf], acc[mf][nf], 0, 0, 0);
      __builtin_amdgcn_s_setprio(0);
      __builtin_amdgcn_s_barrier();        // reads done before next stage lands
    }
    // epilogue for this nt: overlaps next nt's in-flight B stage
    #pragma unroll
    for (int mf = 0; mf < 2; ++mf)
      #pragma unroll
      for (int reg = 0; reg < 4; ++reg) {
        float pp = 0.f;
        #pragma unroll
        for (int nf = 0; nf < 4; ++nf)
          pp += ftanh(acc[mf][nf][reg] + bl[nt][nf]) * vl[nt][nf];
        sp[mf][reg] += pp;
      }
  }

  // reduce over the 16 n-lanes; combine the two nh waves via dead ring space
  float* sRed = (float*)sXs + 4096;        // 16 KiB offset: past sB, untouched
  float pv[2][4];
  #pragma unroll
  for (int mf = 0; mf < 2; ++mf)
    #pragma unroll
    for (int reg = 0; reg < 4; ++reg) {
      float p = sp[mf][reg];
      p += __shfl_xor(p, 1, 16);
      p += __shfl_xor(p, 2, 16);
      p += __shfl_xor(p, 4, 16);
      p += __shfl_xor(p, 8, 16);
      pv[mf][reg] = p;
    }
  if (nh == 1 && lr == 0) {
    #pragma unroll
    for (int mf = 0; mf < 2; ++mf)
      #pragma unroll
      for (int reg = 0; reg < 4; ++reg)
        sRed[((mh * 2 + mf) * 4 + quad) * 4 + reg] = pv[mf][reg];
  }
  __syncthreads();
  if (nh == 0 && lr == 0) {
    #pragma unroll
    for (int mf = 0; mf < 2; ++mf)
      #pragma unroll
      for (int reg = 0; reg < 4; ++reg)
        s[mt * 64 + mh * 32 + mf * 16 + quad * 4 + reg] =
            pv[mf][reg] + sRed[((mh * 2 + mf) * 4 + quad) * 4 + reg];
  }
}

// ---------------------------------------------------------------------------
// pool2 v5: fused windowed-softmax + pooling, reading x in f32 directly
// (xbf eliminated; matches reference precision on the pooling einsum).
// Per (c,p): 4x float4 = one 64-B contiguous window; coalesced across pi.
__global__ __launch_bounds__(256) void pool2(const float* __restrict__ x,
    const float* __restrict__ s, const void* __restrict__ mask,
    const int* __restrict__ flag, float* __restrict__ out) {
  __shared__ float wl[8][17];
  const int t = threadIdx.x;
  const int p0 = blockIdx.x * 8, b = blockIdx.y;
  const int ch = blockIdx.z;
  if (t < 8 && p0 + t < LPOOL) {
    const int p = p0 + t;
    const bool u8 = (*flag != 0);
    const unsigned char* m8 = (const unsigned char*)mask;
    const int* m32 = (const int*)mask;
    const int base = b * Lsz + p * 8;
    float sv[16]; int mv[16];
    float mx = -3.4e38f;
    #pragma unroll
    for (int w = 0; w < 16; ++w) {
      int mk = u8 ? (int)m8[base + w] : m32[base + w];
      float val = mk ? NEGV : s[base + w];
      sv[w] = val; mv[w] = mk;
      mx = fmaxf(mx, val);
    }
    float sum = 0.f;
    #pragma unroll
    for (int w = 0; w < 16; ++w) { sv[w] = expf(sv[w] - mx); sum += sv[w]; }
    float inv = 1.0f / sum;
    float norm = 0.f;
    #pragma unroll
    for (int w = 0; w < 16; ++w) { sv[w] = mv[w] ? 0.f : sv[w] * inv; norm += sv[w]; }
    norm = fmaxf(norm, 1e-6f);
    float rn = 1.0f / norm;
    #pragma unroll
    for (int w = 0; w < 16; ++w) wl[t][w] = sv[w] * rn;
  }
  __syncthreads();
  const int ci = t >> 3, pi = t & 7;
  const int p = p0 + pi;
  if (p >= LPOOL) return;
  float wr[16];
  #pragma unroll
  for (int w = 0; w < 16; ++w) wr[w] = wl[pi][w];
  #pragma unroll
  for (int it = 0; it < 8; ++it) {
    int c = ch * 256 + it * 32 + ci;
    const float* xp = x + ((size_t)b * Csz + c) * Lsz + 8 * p;
    float4 x0 = *(const float4*)(xp);
    float4 x1 = *(const float4*)(xp + 4);
    float4 x2 = *(const float4*)(xp + 8);
    float4 x3 = *(const float4*)(xp + 12);
    float acc = x0.x * wr[0] + x0.y * wr[1] + x0.z * wr[2] + x0.w * wr[3]
              + x1.x * wr[4] + x1.y * wr[5] + x1.z * wr[6] + x1.w * wr[7]
              + x2.x * wr[8] + x2.y * wr[9] + x2.z * wr[10] + x2.w * wr[11]
              + x3.x * wr[12] + x3.y * wr[13] + x3.z * wr[14] + x3.w * wr[15];
    out[((size_t)b * Csz + c) * LPOOL + p] = acc;
  }
}

// ---------------------------------------------------------------------------
// Fallback path kernels (only if ws too small for bf16 path)
__global__ void detect_mask(const unsigned char* __restrict__ mb, int* __restrict__ flag) {
  __shared__ int sf;
  int t = threadIdx.x;
  if (t == 0) sf = 0;
  __syncthreads();
  int f = 0;
  for (int i = t; i < 4096; i += 256)
    if ((i & 3) && mb[i]) f = 1;
  if (f) atomicOr(&sf, 1);
  __syncthreads();
  if (t == 0) *flag = sf;
}

__global__ __launch_bounds__(256) void gemm_s_f32(const float* __restrict__ x,
    const float* __restrict__ W, const float* __restrict__ bias,
    const float* __restrict__ v, float* __restrict__ s_out) {
  __shared__ float sA[32][64];
  __shared__ float sB[32][68];
  __shared__ float s_acc[64];
  const int tid = threadIdx.x;
  const int b = blockIdx.y;
  const int l0 = blockIdx.x * 64;
  if (tid < 64) s_acc[tid] = 0.0f;
  const int tx = tid & 15;
  const int ty = tid >> 4;
  const float* xb = x + ((size_t)b * Csz) * Lsz + l0;
  for (int d0 = 0; d0 < Csz; d0 += 64) {
    float acc[4][4] = {{0.f}};
    for (int c0 = 0; c0 < Csz; c0 += 32) {
      __syncthreads();
      #pragma unroll
      for (int it = 0; it < 8; ++it) {
        int idx = tid + it * 256;
        int kc = idx >> 6, ml = idx & 63;
        sA[kc][ml] = xb[(size_t)(c0 + kc) * Lsz + ml];
      }
      #pragma unroll
      for (int it = 0; it < 8; ++it) {
        int idx = tid + it * 256;
        int kc = idx & 31, dj = idx >> 5;
        sB[kc][dj] = W[(size_t)(d0 + dj) * Csz + c0 + kc];
      }
      __syncthreads();
      #pragma unroll
      for (int kc = 0; kc < 32; ++kc) {
        float4 a  = *(const float4*)(&sA[kc][tx << 2]);
        float4 w4 = *(const float4*)(&sB[kc][ty << 2]);
        acc[0][0] += a.x * w4.x; acc[0][1] += a.x * w4.y; acc[0][2] += a.x * w4.z; acc[0][3] += a.x * w4.w;
        acc[1][0] += a.y * w4.x; acc[1][1] += a.y * w4.y; acc[1][2] += a.y * w4.z; acc[1][3] += a.y * w4.w;
        acc[2][0] += a.z * w4.x; acc[2][1] += a.z * w4.y; acc[2][2] += a.z * w4.z; acc[2][3] += a.z * w4.w;
        acc[3][0] += a.w * w4.x; acc[3][1] += a.w * w4.y; acc[3][2] += a.w * w4.z; acc[3][3] += a.w * w4.w;
      }
    }
    float part[4] = {0.f, 0.f, 0.f, 0.f};
    #pragma unroll
    for (int j = 0; j < 4; ++j) {
      int d = d0 + (ty << 2) + j;
      float bj = bias[d], vj = v[d];
      #pragma unroll
      for (int i = 0; i < 4; ++i)
        part[i] += tanhf(acc[i][j] + bj) * vj;
    }
    #pragma unroll
    for (int i = 0; i < 4; ++i)
      atomicAdd(&s_acc[(tx << 2) + i], part[i]);
  }
  __syncthreads();
  if (tid < 64) s_out[(size_t)b * Lsz + l0 + tid] = s_acc[tid];
}

__global__ void win_weights(const float* __restrict__ s, const void* __restrict__ mask,
                            const int* __restrict__ flag, float* __restrict__ wgt) {
  int t = blockIdx.x * blockDim.x + threadIdx.x;
  if (t >= Bsz * LPOOL) return;
  int b = t / LPOOL, p = t - b * LPOOL;
  const bool u8 = (*flag != 0);
  const unsigned char* m8 = (const unsigned char*)mask;
  const int* m32 = (const int*)mask;
  float sv[16]; int mv[16];
  float mx = -3.4e38f;
  int base = b * Lsz + p * 8;
  #pragma unroll
  for (int w = 0; w < 16; ++w) {
    int mk = u8 ? (int)m8[base + w] : m32[base + w];
    float val = mk ? NEGV : s[base + w];
    sv[w] = val; mv[w] = mk;
    mx = fmaxf(mx, val);
  }
  float sum = 0.f;
  #pragma unroll
  for (int w = 0; w < 16; ++w) { sv[w] = expf(sv[w] - mx); sum += sv[w]; }
  float inv = 1.0f / sum;
  float norm = 0.f;
  #pragma unroll
  for (int w = 0; w < 16; ++w) { sv[w] = mv[w] ? 0.f : sv[w] * inv; norm += sv[w]; }
  norm = fmaxf(norm, 1e-6f);
  float rn = 1.0f / norm;
  #pragma unroll
  for (int w = 0; w < 16; ++w) wgt[t * 16 + w] = sv[w] * rn;
}

__global__ __launch_bounds__(256) void pool_out(const float* __restrict__ x,
    const float* __restrict__ wgt, float* __restrict__ out) {
  __shared__ float xrow[Lsz];
  int bc = blockIdx.x;
  int c = bc & (Csz - 1);
  int b = bc >> 9;
  const float* xr = x + ((size_t)b * Csz + c) * Lsz;
  int tid = threadIdx.x;
  #pragma unroll
  for (int it = 0; it < 4; ++it) {
    int idx = (tid + it * 256) << 2;
    *(float4*)(&xrow[idx]) = *(const float4*)(&xr[idx]);
  }
  __syncthreads();
  const float* wb = wgt + (size_t)b * LPOOL * 16;
  float* ob = out + ((size_t)b * Csz + c) * LPOOL;
  for (int p = tid; p < LPOOL; p += 256) {
    const float4* wp = (const float4*)(wb + p * 16);
    const float4* xp = (const float4*)(&xrow[p * 8]);
    float acc = 0.f;
    #pragma unroll
    for (int q = 0; q < 4; ++q) {
      float4 wv = wp[q], xv = xp[q];
      acc += xv.x * wv.x + xv.y * wv.y + xv.z * wv.z + xv.w * wv.w;
    }
    ob[p] = acc;
  }
}

// ---------------------------------------------------------------------------
extern "C" void kernel_launch(void* const* d_in, const int* in_sizes, int n_in,
                              void* d_out, int out_size, void* d_ws, size_t ws_size,
                              hipStream_t stream) {
  const float* x    = (const float*)d_in[0];
  const void*  mask = d_in[1];
  const float* W    = (const float*)d_in[2];
  const float* bias = (const float*)d_in[3];
  const float* v    = (const float*)d_in[4];
  float* out = (float*)d_out;

  char* wsb = (char*)d_ws;
  int*   flag = (int*)wsb;                                   // 256 B
  float* s    = (float*)(wsb + 256);                         // 131072 B
  float* wgt  = (float*)(wsb + 131328);                      // 261632 B (fallback only)
  __hip_bfloat16* Wts = (__hip_bfloat16*)(wsb + 393216);     // 524288 B
  const size_t NEED = 917504;

  if (ws_size >= NEED) {
    prep<<<129, 256, 0, stream>>>((const unsigned char*)mask, flag, W, Wts);
    gemm_fused<<<512, 256, 0, stream>>>(x, Wts, bias, v, s);
    pool2<<<dim3(64, Bsz, 2), 256, 0, stream>>>(x, s, mask, flag, out);
  } else {
    detect_mask<<<1, 256, 0, stream>>>((const unsigned char*)mask, flag);
    gemm_s_f32<<<dim3(Lsz / 64, Bsz), 256, 0, stream>>>(x, W, bias, v, s);
    win_weights<<<(Bsz * LPOOL + 255) / 256, 256, 0, stream>>>(s, mask, flag, wgt);
    pool_out<<<Bsz * Csz, 256, 0, stream>>>(x, wgt, out);
  }
}

// Round 6
// 149.413 us; speedup vs baseline: 1.2430x; 1.2430x over previous
//
#include <hip/hip_runtime.h>
#include <hip/hip_bf16.h>
#include <cmath>

#define Bsz 8
#define Csz 512
#define Lsz 4096
#define LPOOL 511
#define NEGV -1000000000.0f

typedef __attribute__((ext_vector_type(8))) short short8;
typedef __attribute__((ext_vector_type(4))) float float4v;

__device__ __forceinline__ float bf2f(short u) {
  unsigned int x = ((unsigned int)(unsigned short)u) << 16;
  return __builtin_bit_cast(float, x);
}

// fast tanh: 1 - 2/(e^{2x}+1); rel err ~1e-5, far below bf16 gemm noise
__device__ __forceinline__ float ftanh(float x) {
  float e = __expf(2.0f * x);
  return 1.0f - 2.0f * __builtin_amdgcn_rcpf(e + 1.0f);
}

// ---------------------------------------------------------------------------
// prep: block 0 = mask-width detect; blocks 1..128 = W f32 -> Wts bf16 tiled.
__global__ __launch_bounds__(256) void prep(const unsigned char* __restrict__ mb,
    int* __restrict__ flag, const float* __restrict__ W,
    __hip_bfloat16* __restrict__ Wts) {
  const int tid = threadIdx.x;
  const int pb = blockIdx.x;
  if (pb == 0) {
    __shared__ int sf;
    if (tid == 0) sf = 0;
    __syncthreads();
    int f = 0;
    for (int i = tid; i < 4096; i += 256)
      if ((i & 3) && mb[i]) f = 1;
    if (f) atomicOr(&sf, 1);
    __syncthreads();
    if (tid == 0) *flag = sf;  // 0 = int32 mask, 1 = uint8 mask
  } else {
    int tg = (pb - 1) * 256 + tid;
    int d = tg >> 6, cg = tg & 63;
    float4 w0 = *(const float4*)(W + (size_t)d * 512 + cg * 8);
    float4 w1 = *(const float4*)(W + (size_t)d * 512 + cg * 8 + 4);
    __hip_bfloat16 hb[8];
    hb[0] = __float2bfloat16(w0.x); hb[1] = __float2bfloat16(w0.y);
    hb[2] = __float2bfloat16(w0.z); hb[3] = __float2bfloat16(w0.w);
    hb[4] = __float2bfloat16(w1.x); hb[5] = __float2bfloat16(w1.y);
    hb[6] = __float2bfloat16(w1.z); hb[7] = __float2bfloat16(w1.w);
    int nt = d >> 7, row = d & 127, ks = cg >> 2, seg = cg & 3;
    *(short8*)(Wts + (((size_t)nt * 16 + ks) * 512 + seg * 128 + row) * 8) = *(short8*)hb;
  }
}

// ---------------------------------------------------------------------------
// gemm_fused v6: 512 blocks x 256 thr (4 waves), 64 m-rows each, 74.5 KiB LDS
// -> 2 blocks/CU. NO barriers in any hot loop.
// Phase 1: per-wave transpose (wave owns 16 l-cols): f32 global (depth-3
// prefetch) -> elementwise LDS stage (pitch 21, full bank spread) -> strided
// read (2-way, free) -> cvt bf16 -> ds_write_b128 into MFMA-tiled sA.
// Compiler-counted lgkm waits only (in-order per-wave DS pipe).
// Phase 2: barrier-FREE k-loop. A-frags from read-only sA; B-frags loaded
// directly from L2-resident Wts into a register ping-pong (bA/bB), one k-step
// ahead. Waves run independently; 8 waves/CU hide L2 latency.
// Per-nt tanh epilogue in registers; single syncthreads before final reduce.
__global__ __launch_bounds__(256, 2) void gemm_fused(
    const float* __restrict__ x, const __hip_bfloat16* __restrict__ Wts,
    const float* __restrict__ bias, const float* __restrict__ v,
    float* __restrict__ s) {
  __shared__ short8 sA[4096];                    // 64 KiB: A 64m x 512k tiled
  __shared__ float sXw4[4][672];                 // 10.5 KiB: per-wave [32][21]

  const int tid = threadIdx.x;
  const int lane = tid & 63, wave = tid >> 6;
  const int mt = blockIdx.x;                     // 0..511
  const int b = mt >> 6;
  const int l0 = (mt & 63) << 6;                 // 64 l-rows per block

  // ---------------- phase 1: per-wave transpose, no waits beyond compiler's --
  {
    float* sXw = sXw4[wave];
    const int r = lane >> 1;                     // c-row within 32-c chunk
    const int q = lane & 1;                      // 8-float half of wave's 16 l
    const int ll = lane & 15, ks2 = lane >> 4;   // read-side task
    const float* xg = x + (((size_t)(b * Csz + r)) << 12) + (size_t)(l0 + wave * 16 + q * 8);

    float4 A0a = *(const float4*)(xg);
    float4 A0b = *(const float4*)(xg + 4);
    float4 A1a = *(const float4*)(xg + (1u << 17));
    float4 A1b = *(const float4*)(xg + (1u << 17) + 4);
    float4 A2a = *(const float4*)(xg + (2u << 17));
    float4 A2b = *(const float4*)(xg + (2u << 17) + 4);

    #pragma unroll
    for (int cc = 0; cc < 16; ++cc) {
      float4 Na = A2a, Nb = A2b;
      if (cc < 13) {
        const float* xn = xg + ((size_t)(cc + 3) << 17);
        Na = *(const float4*)(xn);
        Nb = *(const float4*)(xn + 4);
      }
      // stage 8 floats elementwise (pitch 21: banks fully spread)
      float* wp = &sXw[r * 21 + q * 8];
      wp[0] = A0a.x; wp[1] = A0a.y; wp[2] = A0a.z; wp[3] = A0a.w;
      wp[4] = A0b.x; wp[5] = A0b.y; wp[6] = A0b.z; wp[7] = A0b.w;
      // transposed read: 8 consecutive c's for one l (2-way banks, free)
      float tv[8];
      #pragma unroll
      for (int j = 0; j < 8; ++j) tv[j] = sXw[(ks2 * 8 + j) * 21 + ll];
      __hip_bfloat16 ab[8];
      #pragma unroll
      for (int j = 0; j < 8; ++j) ab[j] = __float2bfloat16(tv[j]);
      sA[(cc * 4 + ks2) * 64 + wave * 16 + ll] = *(short8*)ab;
      A0a = A1a; A0b = A1b; A1a = A2a; A1b = A2b; A2a = Na; A2b = Nb;
    }
  }

  const int lr = lane & 15, quad = lane >> 4;
  const int mh = wave >> 1, nh = wave & 1;

  __syncthreads();   // sA complete; phase 2 is read-only on LDS -> no more sync

  // ---------------- phase 2: barrier-free nt/k loop -------------------------
  const short8* Bp = (const short8*)Wts + quad * 128 + nh * 64 + lr;
#define LDB(dst, idx)                                                          \
  {                                                                            \
    const short8* bp = Bp + ((size_t)(idx) << 9);                              \
    dst[0] = bp[0]; dst[1] = bp[16]; dst[2] = bp[32]; dst[3] = bp[48];         \
  }
  short8 bA[4], bB[4];
  LDB(bA, 0)

  float sp[2][4];
  #pragma unroll
  for (int mf = 0; mf < 2; ++mf)
    #pragma unroll
    for (int reg = 0; reg < 4; ++reg) sp[mf][reg] = 0.f;

  #pragma unroll
  for (int nt = 0; nt < 4; ++nt) {
    // bias/v fragments for this nt (L1-hot; reloading saves 24 VGPR)
    float bl[4], vl[4];
    #pragma unroll
    for (int nf = 0; nf < 4; ++nf) {
      int n = nt * 128 + nh * 64 + nf * 16 + lr;
      bl[nf] = bias[n];
      vl[nf] = v[n];
    }
    float4v acc[2][4];
    #pragma unroll
    for (int mf = 0; mf < 2; ++mf)
      #pragma unroll
      for (int nf = 0; nf < 4; ++nf) acc[mf][nf] = (float4v)0.f;

    #pragma unroll
    for (int k2 = 0; k2 < 8; ++k2) {
      const int ks = k2 * 2;
      const int idx = nt * 16 + ks;
      if (idx + 1 < 64) LDB(bB, idx + 1)
      {
        short8 af[2];
        #pragma unroll
        for (int mf = 0; mf < 2; ++mf)
          af[mf] = sA[(ks * 4 + quad) * 64 + mh * 32 + mf * 16 + lr];
        __builtin_amdgcn_s_setprio(1);
        #pragma unroll
        for (int mf = 0; mf < 2; ++mf)
          #pragma unroll
          for (int nf = 0; nf < 4; ++nf)
            acc[mf][nf] = __builtin_amdgcn_mfma_f32_16x16x32_bf16(
                af[mf], bA[nf], acc[mf][nf], 0, 0, 0);
        __builtin_amdgcn_s_setprio(0);
      }
      if (idx + 2 < 64) LDB(bA, idx + 2)
      {
        short8 af[2];
        #pragma unroll
        for (int mf = 0; mf < 2; ++mf)
          af[mf] = sA[((ks + 1) * 4 + quad) * 64 + mh * 32 + mf * 16 + lr];
        __builtin_amdgcn_s_setprio(1);
        #pragma unroll
        for (int mf = 0; mf < 2; ++mf)
          #pragma unroll
          for (int nf = 0; nf < 4; ++nf)
            acc[mf][nf] = __builtin_amdgcn_mfma_f32_16x16x32_bf16(
                af[mf], bB[nf], acc[mf][nf], 0, 0, 0);
        __builtin_amdgcn_s_setprio(0);
      }
    }
    // epilogue for this nt (no sync needed; pure registers)
    #pragma unroll
    for (int mf = 0; mf < 2; ++mf)
      #pragma unroll
      for (int reg = 0; reg < 4; ++reg) {
        float pp = 0.f;
        #pragma unroll
        for (int nf = 0; nf < 4; ++nf)
          pp += ftanh(acc[mf][nf][reg] + bl[nf]) * vl[nf];
        sp[mf][reg] += pp;
      }
  }
#undef LDB

  // reduce over the 16 n-lanes; combine the two nh waves via staging space
  float* sRed = (float*)sXw4;              // 64 floats needed; sXw dead
  float pv[2][4];
  #pragma unroll
  for (int mf = 0; mf < 2; ++mf)
    #pragma unroll
    for (int reg = 0; reg < 4; ++reg) {
      float p = sp[mf][reg];
      p += __shfl_xor(p, 1, 16);
      p += __shfl_xor(p, 2, 16);
      p += __shfl_xor(p, 4, 16);
      p += __shfl_xor(p, 8, 16);
      pv[mf][reg] = p;
    }
  __syncthreads();                         // re-sync drifted waves before sRed
  if (nh == 1 && lr == 0) {
    #pragma unroll
    for (int mf = 0; mf < 2; ++mf)
      #pragma unroll
      for (int reg = 0; reg < 4; ++reg)
        sRed[((mh * 2 + mf) * 4 + quad) * 4 + reg] = pv[mf][reg];
  }
  __syncthreads();
  if (nh == 0 && lr == 0) {
    #pragma unroll
    for (int mf = 0; mf < 2; ++mf)
      #pragma unroll
      for (int reg = 0; reg < 4; ++reg)
        s[mt * 64 + mh * 32 + mf * 16 + quad * 4 + reg] =
            pv[mf][reg] + sRed[((mh * 2 + mf) * 4 + quad) * 4 + reg];
  }
}

// ---------------------------------------------------------------------------
// pool2: fused windowed-softmax + pooling, reading x in f32 directly.
// Per (c,p): 4x float4 = one 64-B contiguous window; coalesced across pi.
__global__ __launch_bounds__(256) void pool2(const float* __restrict__ x,
    const float* __restrict__ s, const void* __restrict__ mask,
    const int* __restrict__ flag, float* __restrict__ out) {
  __shared__ float wl[8][17];
  const int t = threadIdx.x;
  const int p0 = blockIdx.x * 8, b = blockIdx.y;
  const int ch = blockIdx.z;
  if (t < 8 && p0 + t < LPOOL) {
    const int p = p0 + t;
    const bool u8 = (*flag != 0);
    const unsigned char* m8 = (const unsigned char*)mask;
    const int* m32 = (const int*)mask;
    const int base = b * Lsz + p * 8;
    float sv[16]; int mv[16];
    float mx = -3.4e38f;
    #pragma unroll
    for (int w = 0; w < 16; ++w) {
      int mk = u8 ? (int)m8[base + w] : m32[base + w];
      float val = mk ? NEGV : s[base + w];
      sv[w] = val; mv[w] = mk;
      mx = fmaxf(mx, val);
    }
    float sum = 0.f;
    #pragma unroll
    for (int w = 0; w < 16; ++w) { sv[w] = expf(sv[w] - mx); sum += sv[w]; }
    float inv = 1.0f / sum;
    float norm = 0.f;
    #pragma unroll
    for (int w = 0; w < 16; ++w) { sv[w] = mv[w] ? 0.f : sv[w] * inv; norm += sv[w]; }
    norm = fmaxf(norm, 1e-6f);
    float rn = 1.0f / norm;
    #pragma unroll
    for (int w = 0; w < 16; ++w) wl[t][w] = sv[w] * rn;
  }
  __syncthreads();
  const int ci = t >> 3, pi = t & 7;
  const int p = p0 + pi;
  if (p >= LPOOL) return;
  float wr[16];
  #pragma unroll
  for (int w = 0; w < 16; ++w) wr[w] = wl[pi][w];
  #pragma unroll
  for (int it = 0; it < 8; ++it) {
    int c = ch * 256 + it * 32 + ci;
    const float* xp = x + ((size_t)b * Csz + c) * Lsz + 8 * p;
    float4 x0 = *(const float4*)(xp);
    float4 x1 = *(const float4*)(xp + 4);
    float4 x2 = *(const float4*)(xp + 8);
    float4 x3 = *(const float4*)(xp + 12);
    float acc = x0.x * wr[0] + x0.y * wr[1] + x0.z * wr[2] + x0.w * wr[3]
              + x1.x * wr[4] + x1.y * wr[5] + x1.z * wr[6] + x1.w * wr[7]
              + x2.x * wr[8] + x2.y * wr[9] + x2.z * wr[10] + x2.w * wr[11]
              + x3.x * wr[12] + x3.y * wr[13] + x3.z * wr[14] + x3.w * wr[15];
    out[((size_t)b * Csz + c) * LPOOL + p] = acc;
  }
}

// ---------------------------------------------------------------------------
// Fallback path kernels (only if ws too small for bf16 path)
__global__ void detect_mask(const unsigned char* __restrict__ mb, int* __restrict__ flag) {
  __shared__ int sf;
  int t = threadIdx.x;
  if (t == 0) sf = 0;
  __syncthreads();
  int f = 0;
  for (int i = t; i < 4096; i += 256)
    if ((i & 3) && mb[i]) f = 1;
  if (f) atomicOr(&sf, 1);
  __syncthreads();
  if (t == 0) *flag = sf;
}

__global__ __launch_bounds__(256) void gemm_s_f32(const float* __restrict__ x,
    const float* __restrict__ W, const float* __restrict__ bias,
    const float* __restrict__ v, float* __restrict__ s_out) {
  __shared__ float sA[32][64];
  __shared__ float sB[32][68];
  __shared__ float s_acc[64];
  const int tid = threadIdx.x;
  const int b = blockIdx.y;
  const int l0 = blockIdx.x * 64;
  if (tid < 64) s_acc[tid] = 0.0f;
  const int tx = tid & 15;
  const int ty = tid >> 4;
  const float* xb = x + ((size_t)b * Csz) * Lsz + l0;
  for (int d0 = 0; d0 < Csz; d0 += 64) {
    float acc[4][4] = {{0.f}};
    for (int c0 = 0; c0 < Csz; c0 += 32) {
      __syncthreads();
      #pragma unroll
      for (int it = 0; it < 8; ++it) {
        int idx = tid + it * 256;
        int kc = idx >> 6, ml = idx & 63;
        sA[kc][ml] = xb[(size_t)(c0 + kc) * Lsz + ml];
      }
      #pragma unroll
      for (int it = 0; it < 8; ++it) {
        int idx = tid + it * 256;
        int kc = idx & 31, dj = idx >> 5;
        sB[kc][dj] = W[(size_t)(d0 + dj) * Csz + c0 + kc];
      }
      __syncthreads();
      #pragma unroll
      for (int kc = 0; kc < 32; ++kc) {
        float4 a  = *(const float4*)(&sA[kc][tx << 2]);
        float4 w4 = *(const float4*)(&sB[kc][ty << 2]);
        acc[0][0] += a.x * w4.x; acc[0][1] += a.x * w4.y; acc[0][2] += a.x * w4.z; acc[0][3] += a.x * w4.w;
        acc[1][0] += a.y * w4.x; acc[1][1] += a.y * w4.y; acc[1][2] += a.y * w4.z; acc[1][3] += a.y * w4.w;
        acc[2][0] += a.z * w4.x; acc[2][1] += a.z * w4.y; acc[2][2] += a.z * w4.z; acc[2][3] += a.z * w4.w;
        acc[3][0] += a.w * w4.x; acc[3][1] += a.w * w4.y; acc[3][2] += a.w * w4.z; acc[3][3] += a.w * w4.w;
      }
    }
    float part[4] = {0.f, 0.f, 0.f, 0.f};
    #pragma unroll
    for (int j = 0; j < 4; ++j) {
      int d = d0 + (ty << 2) + j;
      float bj = bias[d], vj = v[d];
      #pragma unroll
      for (int i = 0; i < 4; ++i)
        part[i] += tanhf(acc[i][j] + bj) * vj;
    }
    #pragma unroll
    for (int i = 0; i < 4; ++i)
      atomicAdd(&s_acc[(tx << 2) + i], part[i]);
  }
  __syncthreads();
  if (tid < 64) s_out[(size_t)b * Lsz + l0 + tid] = s_acc[tid];
}

__global__ void win_weights(const float* __restrict__ s, const void* __restrict__ mask,
                            const int* __restrict__ flag, float* __restrict__ wgt) {
  int t = blockIdx.x * blockDim.x + threadIdx.x;
  if (t >= Bsz * LPOOL) return;
  int b = t / LPOOL, p = t - b * LPOOL;
  const bool u8 = (*flag != 0);
  const unsigned char* m8 = (const unsigned char*)mask;
  const int* m32 = (const int*)mask;
  float sv[16]; int mv[16];
  float mx = -3.4e38f;
  int base = b * Lsz + p * 8;
  #pragma unroll
  for (int w = 0; w < 16; ++w) {
    int mk = u8 ? (int)m8[base + w] : m32[base + w];
    float val = mk ? NEGV : s[base + w];
    sv[w] = val; mv[w] = mk;
    mx = fmaxf(mx, val);
  }
  float sum = 0.f;
  #pragma unroll
  for (int w = 0; w < 16; ++w) { sv[w] = expf(sv[w] - mx); sum += sv[w]; }
  float inv = 1.0f / sum;
  float norm = 0.f;
  #pragma unroll
  for (int w = 0; w < 16; ++w) { sv[w] = mv[w] ? 0.f : sv[w] * inv; norm += sv[w]; }
  norm = fmaxf(norm, 1e-6f);
  float rn = 1.0f / norm;
  #pragma unroll
  for (int w = 0; w < 16; ++w) wgt[t * 16 + w] = sv[w] * rn;
}

__global__ __launch_bounds__(256) void pool_out(const float* __restrict__ x,
    const float* __restrict__ wgt, float* __restrict__ out) {
  __shared__ float xrow[Lsz];
  int bc = blockIdx.x;
  int c = bc & (Csz - 1);
  int b = bc >> 9;
  const float* xr = x + ((size_t)b * Csz + c) * Lsz;
  int tid = threadIdx.x;
  #pragma unroll
  for (int it = 0; it < 4; ++it) {
    int idx = (tid + it * 256) << 2;
    *(float4*)(&xrow[idx]) = *(const float4*)(&xr[idx]);
  }
  __syncthreads();
  const float* wb = wgt + (size_t)b * LPOOL * 16;
  float* ob = out + ((size_t)b * Csz + c) * LPOOL;
  for (int p = tid; p < LPOOL; p += 256) {
    const float4* wp = (const float4*)(wb + p * 16);
    const float4* xp = (const float4*)(&xrow[p * 8]);
    float acc = 0.f;
    #pragma unroll
    for (int q = 0; q < 4; ++q) {
      float4 wv = wp[q], xv = xp[q];
      acc += xv.x * wv.x + xv.y * wv.y + xv.z * wv.z + xv.w * wv.w;
    }
    ob[p] = acc;
  }
}

// ---------------------------------------------------------------------------
extern "C" void kernel_launch(void* const* d_in, const int* in_sizes, int n_in,
                              void* d_out, int out_size, void* d_ws, size_t ws_size,
                              hipStream_t stream) {
  const float* x    = (const float*)d_in[0];
  const void*  mask = d_in[1];
  const float* W    = (const float*)d_in[2];
  const float* bias = (const float*)d_in[3];
  const float* v    = (const float*)d_in[4];
  float* out = (float*)d_out;

  char* wsb = (char*)d_ws;
  int*   flag = (int*)wsb;                                   // 256 B
  float* s    = (float*)(wsb + 256);                         // 131072 B
  float* wgt  = (float*)(wsb + 131328);                      // 261632 B (fallback only)
  __hip_bfloat16* Wts = (__hip_bfloat16*)(wsb + 393216);     // 524288 B
  const size_t NEED = 917504;

  if (ws_size >= NEED) {
    prep<<<129, 256, 0, stream>>>((const unsigned char*)mask, flag, W, Wts);
    gemm_fused<<<512, 256, 0, stream>>>(x, Wts, bias, v, s);
    pool2<<<dim3(64, Bsz, 2), 256, 0, stream>>>(x, s, mask, flag, out);
  } else {
    detect_mask<<<1, 256, 0, stream>>>((const unsigned char*)mask, flag);
    gemm_s_f32<<<dim3(Lsz / 64, Bsz), 256, 0, stream>>>(x, W, bias, v, s);
    win_weights<<<(Bsz * LPOOL + 255) / 256, 256, 0, stream>>>(s, mask, flag, wgt);
    pool_out<<<Bsz * Csz, 256, 0, stream>>>(x, wgt, out);
  }
}